// Round 1
// baseline (896.346 us; speedup 1.0000x reference)
//
#include <hip/hip_runtime.h>
#include <hip/hip_bf16.h>

#define N_NODES 100000
#define D 256
#define R_REL 8
#define E_EDGES 40000
#define B_BASES 4
#define LN_EPS 1e-5f

#define COMP(v,k) ((k)==0?(v).x:(k)==1?(v).y:(k)==2?(v).z:(v).w)

// ---------------------------------------------------------------------------
// W[r,d,o] = sum_b coeff[r,b] * bases[b,d,o]
__global__ void k_compute_W(const float* __restrict__ bases,
                            const float* __restrict__ coeff,
                            float* __restrict__ W) {
    int idx = blockIdx.x * blockDim.x + threadIdx.x;
    if (idx >= R_REL * D * D) return;
    int r = idx / (D * D);
    int rem = idx % (D * D);
    float acc = 0.f;
#pragma unroll
    for (int b = 0; b < B_BASES; ++b)
        acc += coeff[r * B_BASES + b] * bases[b * D * D + rem];
    W[idx] = acc;
}

// ---------------------------------------------------------------------------
// deg[r,n] += 1 for each edge (r, *, dst=n)
__global__ void k_count(const int* __restrict__ ei, float* __restrict__ deg) {
    int idx = blockIdx.x * blockDim.x + threadIdx.x;
    if (idx >= R_REL * E_EDGES) return;
    int r = idx / E_EDGES, e = idx % E_EDGES;
    int dst = ei[(r * 2 + 1) * E_EDGES + e];
    atomicAdd(&deg[r * N_NODES + dst], 1.0f);
}

// deg -> 1/max(deg,1)
__global__ void k_invdeg(float* __restrict__ deg) {
    int idx = blockIdx.x * blockDim.x + threadIdx.x;
    if (idx < R_REL * N_NODES) deg[idx] = 1.0f / fmaxf(deg[idx], 1.0f);
}

// ---------------------------------------------------------------------------
// h = x @ w_self + b_self  -> out   (32 rows per 256-thread block)
__global__ __launch_bounds__(256) void k_self(const float* __restrict__ x,
                                              const float* __restrict__ w,
                                              const float* __restrict__ b,
                                              float* __restrict__ out) {
    __shared__ float xs[32][D];                 // 32 KB
    int t = threadIdx.x;
    int row0 = blockIdx.x * 32;
    // stage 32 rows: 4 rows per iteration, float4 per thread
    for (int i = 0; i < 8; ++i) {
        int rr = i * 4 + (t >> 6);
        int cc = (t & 63) * 4;
        *(float4*)&xs[rr][cc] = *(const float4*)&x[(size_t)(row0 + rr) * D + cc];
    }
    __syncthreads();
    int c = t & 63, g = t >> 6;                 // col base, row group (8 rows each)
    float acc[8][4] = {};
    for (int d = 0; d < D; d += 4) {
        float4 xv[8];
#pragma unroll
        for (int i = 0; i < 8; ++i) xv[i] = *(const float4*)&xs[g * 8 + i][d];
#pragma unroll
        for (int k = 0; k < 4; ++k) {
            float w0 = w[(d + k) * D + c];
            float w1 = w[(d + k) * D + c + 64];
            float w2 = w[(d + k) * D + c + 128];
            float w3 = w[(d + k) * D + c + 192];
#pragma unroll
            for (int i = 0; i < 8; ++i) {
                float xk = COMP(xv[i], k);
                acc[i][0] += xk * w0; acc[i][1] += xk * w1;
                acc[i][2] += xk * w2; acc[i][3] += xk * w3;
            }
        }
    }
    float b0 = b[c], b1 = b[c + 64], b2 = b[c + 128], b3 = b[c + 192];
#pragma unroll
    for (int i = 0; i < 8; ++i) {
        size_t ro = (size_t)(row0 + g * 8 + i) * D;
        out[ro + c]       = acc[i][0] + b0;
        out[ro + c + 64]  = acc[i][1] + b1;
        out[ro + c + 128] = acc[i][2] + b2;
        out[ro + c + 192] = acc[i][3] + b3;
    }
}

// ---------------------------------------------------------------------------
// per 64-edge tile of relation r: msg = x[src] @ W[r]; atomic scatter *inv_deg
__global__ __launch_bounds__(256) void k_edge(const float* __restrict__ x,
                                              const int* __restrict__ ei,
                                              const float* __restrict__ W,
                                              const float* __restrict__ invdeg,
                                              float* __restrict__ out) {
    __shared__ float xs[64][D];                 // exactly 64 KB
    int t = threadIdx.x;
    const int CHUNKS = E_EDGES / 64;            // 625
    int r = blockIdx.x / CHUNKS;
    int e0 = (blockIdx.x % CHUNKS) * 64;
    // stage 64 gathered rows: 4 rows per iteration (src read is wave-broadcast)
    for (int i = 0; i < 16; ++i) {
        int rr = i * 4 + (t >> 6);
        int src = ei[r * 2 * E_EDGES + e0 + rr];
        int cc = (t & 63) * 4;
        *(float4*)&xs[rr][cc] = *(const float4*)&x[(size_t)src * D + cc];
    }
    __syncthreads();
    int c = t & 63, g = t >> 6;                 // col base, row group (16 rows)
    const float* __restrict__ Wr = W + (size_t)r * D * D;
    float acc[16][4] = {};
    for (int d = 0; d < D; d += 4) {
        float4 xv[16];
#pragma unroll
        for (int i = 0; i < 16; ++i) xv[i] = *(const float4*)&xs[g * 16 + i][d];
#pragma unroll
        for (int k = 0; k < 4; ++k) {
            float w0 = Wr[(d + k) * D + c];
            float w1 = Wr[(d + k) * D + c + 64];
            float w2 = Wr[(d + k) * D + c + 128];
            float w3 = Wr[(d + k) * D + c + 192];
#pragma unroll
            for (int i = 0; i < 16; ++i) {
                float xk = COMP(xv[i], k);
                acc[i][0] += xk * w0; acc[i][1] += xk * w1;
                acc[i][2] += xk * w2; acc[i][3] += xk * w3;
            }
        }
    }
#pragma unroll 4
    for (int i = 0; i < 16; ++i) {
        int row = g * 16 + i;
        int dst = ei[(r * 2 + 1) * E_EDGES + e0 + row];      // wave-broadcast
        float sc = invdeg[r * N_NODES + dst];
        size_t ro = (size_t)dst * D;
        atomicAdd(&out[ro + c],       acc[i][0] * sc);
        atomicAdd(&out[ro + c + 64],  acc[i][1] * sc);
        atomicAdd(&out[ro + c + 128], acc[i][2] * sc);
        atomicAdd(&out[ro + c + 192], acc[i][3] * sc);
    }
}

// ---------------------------------------------------------------------------
// in-place SiLU + LayerNorm, one wave per row (4 rows / 256-thread block)
__global__ __launch_bounds__(256) void k_ln(float* __restrict__ out,
                                            const float* __restrict__ gamma,
                                            const float* __restrict__ beta) {
    int t = threadIdx.x;
    int lane = t & 63, wv = t >> 6;
    int row = blockIdx.x * 4 + wv;
    size_t ro = (size_t)row * D + lane * 4;
    float4 h4 = *(const float4*)&out[ro];
    float a[4];
    a[0] = h4.x / (1.f + expf(-h4.x));
    a[1] = h4.y / (1.f + expf(-h4.y));
    a[2] = h4.z / (1.f + expf(-h4.z));
    a[3] = h4.w / (1.f + expf(-h4.w));
    float s = a[0] + a[1] + a[2] + a[3];
#pragma unroll
    for (int off = 32; off >= 1; off >>= 1) s += __shfl_xor(s, off, 64);
    float mean = s * (1.0f / 256.0f);
    float v = 0.f;
#pragma unroll
    for (int j = 0; j < 4; ++j) { float dd = a[j] - mean; v += dd * dd; }
#pragma unroll
    for (int off = 32; off >= 1; off >>= 1) v += __shfl_xor(v, off, 64);
    float rs = rsqrtf(v * (1.0f / 256.0f) + LN_EPS);
    float4 g4 = *(const float4*)&gamma[lane * 4];
    float4 b4 = *(const float4*)&beta[lane * 4];
    float4 o4;
    o4.x = (a[0] - mean) * rs * g4.x + b4.x;
    o4.y = (a[1] - mean) * rs * g4.y + b4.y;
    o4.z = (a[2] - mean) * rs * g4.z + b4.z;
    o4.w = (a[3] - mean) * rs * g4.w + b4.w;
    *(float4*)&out[ro] = o4;
}

// ---------------------------------------------------------------------------
extern "C" void kernel_launch(void* const* d_in, const int* in_sizes, int n_in,
                              void* d_out, int out_size, void* d_ws, size_t ws_size,
                              hipStream_t stream) {
    const float* x      = (const float*)d_in[0];
    const int*   ei     = (const int*)d_in[1];
    const float* bases  = (const float*)d_in[2];
    const float* coeff  = (const float*)d_in[3];
    const float* w_self = (const float*)d_in[4];
    const float* b_self = (const float*)d_in[5];
    const float* gamma  = (const float*)d_in[6];
    const float* beta   = (const float*)d_in[7];
    float* out = (float*)d_out;

    float* W   = (float*)d_ws;                       // R*D*D floats (2 MB)
    float* deg = W + (size_t)R_REL * D * D;          // R*N floats (3.2 MB)

    hipMemsetAsync(deg, 0, (size_t)R_REL * N_NODES * sizeof(float), stream);

    k_compute_W<<<(R_REL * D * D + 255) / 256, 256, 0, stream>>>(bases, coeff, W);
    k_count<<<(R_REL * E_EDGES + 255) / 256, 256, 0, stream>>>(ei, deg);
    k_invdeg<<<(R_REL * N_NODES + 255) / 256, 256, 0, stream>>>(deg);
    k_self<<<N_NODES / 32, 256, 0, stream>>>(x, w_self, b_self, out);
    k_edge<<<R_REL * (E_EDGES / 64), 256, 0, stream>>>(x, ei, W, deg, out);
    k_ln<<<N_NODES / 4, 256, 0, stream>>>(out, gamma, beta);
}

// Round 2
// 447.297 us; speedup vs baseline: 2.0039x; 2.0039x over previous
//
#include <hip/hip_runtime.h>
#include <hip/hip_bf16.h>

#define N_NODES 100000
#define D 256
#define R_REL 8
#define E_EDGES 40000
#define B_BASES 4
#define LN_EPS 1e-5f

typedef __attribute__((ext_vector_type(8))) short short8;
typedef __attribute__((ext_vector_type(4))) float f32x4;

__device__ inline short bf16_of(float f) {
    __hip_bfloat16 h = __float2bfloat16(f);
    return *reinterpret_cast<short*>(&h);
}

// ---------------------------------------------------------------------------
// Wt[r][o][d] = sum_b coeff[r,b] * bases[b][d][o]   (bf16, transposed)
// 64x64 tile transpose via LDS. grid = R * 4 * 4
__global__ __launch_bounds__(256) void k_prepW(const float* __restrict__ bases,
                                               const float* __restrict__ coeff,
                                               ushort* __restrict__ Wt) {
    __shared__ float tile[64][65];
    int r  = blockIdx.x >> 4;
    int dt = (blockIdx.x >> 2) & 3, ot = blockIdx.x & 3;
    int t = threadIdx.x;
    float c0 = coeff[r * 4 + 0], c1 = coeff[r * 4 + 1];
    float c2 = coeff[r * 4 + 2], c3 = coeff[r * 4 + 3];
    int cl = t & 63, rw = t >> 6;
    for (int i = 0; i < 16; ++i) {
        int dl = i * 4 + rw;
        size_t gi = (size_t)(dt * 64 + dl) * D + ot * 64 + cl;
        tile[dl][cl] = c0 * bases[gi] + c1 * bases[65536 + gi]
                     + c2 * bases[2 * 65536 + gi] + c3 * bases[3 * 65536 + gi];
    }
    __syncthreads();
    for (int i = 0; i < 16; ++i) {
        int ol = i * 4 + rw;
        Wt[(size_t)r * 65536 + (size_t)(ot * 64 + ol) * D + dt * 64 + cl] =
            (ushort)bf16_of(tile[cl][ol]);
    }
}

// wt_self[o][d] = bf16(w_self[d][o]).  grid = 4*4
__global__ __launch_bounds__(256) void k_wselfT(const float* __restrict__ w,
                                                ushort* __restrict__ Wt) {
    __shared__ float tile[64][65];
    int dt = blockIdx.x >> 2, ot = blockIdx.x & 3;
    int t = threadIdx.x;
    int cl = t & 63, rw = t >> 6;
    for (int i = 0; i < 16; ++i) {
        int dl = i * 4 + rw;
        tile[dl][cl] = w[(size_t)(dt * 64 + dl) * D + ot * 64 + cl];
    }
    __syncthreads();
    for (int i = 0; i < 16; ++i) {
        int ol = i * 4 + rw;
        Wt[(size_t)(ot * 64 + ol) * D + dt * 64 + cl] = (ushort)bf16_of(tile[cl][ol]);
    }
}

// ---------------------------------------------------------------------------
__global__ void k_count(const int* __restrict__ ei, float* __restrict__ deg) {
    int idx = blockIdx.x * blockDim.x + threadIdx.x;
    if (idx >= R_REL * E_EDGES) return;
    int r = idx / E_EDGES, e = idx % E_EDGES;
    int dst = ei[(r * 2 + 1) * E_EDGES + e];
    atomicAdd(&deg[r * N_NODES + dst], 1.0f);
}

__global__ void k_invdeg(float* __restrict__ deg) {
    int idx = blockIdx.x * blockDim.x + threadIdx.x;
    if (idx < R_REL * N_NODES) deg[idx] = 1.0f / fmaxf(deg[idx], 1.0f);
}

// ---------------------------------------------------------------------------
// Shared MFMA tile machinery: 64 rows x 256 cols per block, 4 waves.
// LDS layout: xs[row][chunk] of short8 (8 bf16 = 16B), chunk XOR-swizzled.
__device__ inline void stage_row(short8* xs, const float* __restrict__ src_row,
                                 int rr, int c) {
    const float4* xp = (const float4*)(src_row + c * 8);
    float4 f0 = xp[0], f1 = xp[1];
    short8 v;
    v[0] = bf16_of(f0.x); v[1] = bf16_of(f0.y); v[2] = bf16_of(f0.z); v[3] = bf16_of(f0.w);
    v[4] = bf16_of(f1.x); v[5] = bf16_of(f1.y); v[6] = bf16_of(f1.z); v[7] = bf16_of(f1.w);
    xs[rr * 32 + (c ^ (rr & 7))] = v;
}

// msg = x[src] @ W_r, scatter-add *inv_deg.  grid = R * (E/64)
__global__ __launch_bounds__(256) void k_edge(const float* __restrict__ x,
                                              const int* __restrict__ ei,
                                              const ushort* __restrict__ Wt,
                                              const float* __restrict__ invdeg,
                                              float* __restrict__ out) {
    __shared__ short8 xs[64 * 32];               // 32 KB
    int t = threadIdx.x;
    const int CHUNKS = E_EDGES / 64;             // 625
    int r = blockIdx.x / CHUNKS;
    int e0 = (blockIdx.x % CHUNKS) * 64;
    const int* ei_src = ei + r * 2 * E_EDGES;
    const int* ei_dst = ei_src + E_EDGES;
    {
        int c = t & 31, rbase = t >> 5;
        for (int i = 0; i < 8; ++i) {
            int rr = i * 8 + rbase;
            int src = ei_src[e0 + rr];
            stage_row(xs, x + (size_t)src * D, rr, c);
        }
    }
    __syncthreads();
    int l = t & 63, w = t >> 6;
    int colbase = w * 64;
    int lr = l & 15, lg = l >> 4;
    const ushort* Wr = Wt + (size_t)r * D * D;
    f32x4 acc[4][4] = {};
    for (int kk = 0; kk < 8; ++kk) {
        short8 a[4], b[4];
#pragma unroll
        for (int mi = 0; mi < 4; ++mi) {
            int row = mi * 16 + lr;
            int ch = kk * 4 + lg;
            a[mi] = xs[row * 32 + (ch ^ (row & 7))];
        }
#pragma unroll
        for (int ni = 0; ni < 4; ++ni) {
            int col = colbase + ni * 16 + lr;
            b[ni] = *reinterpret_cast<const short8*>(Wr + (size_t)col * D + kk * 32 + lg * 8);
        }
#pragma unroll
        for (int mi = 0; mi < 4; ++mi)
#pragma unroll
            for (int ni = 0; ni < 4; ++ni)
                acc[mi][ni] = __builtin_amdgcn_mfma_f32_16x16x32_bf16(
                    a[mi], b[ni], acc[mi][ni], 0, 0, 0);
    }
    // scatter: D frag mapping col=lane&15, row=(lane>>4)*4+reg  [m89]
#pragma unroll
    for (int mi = 0; mi < 4; ++mi) {
#pragma unroll
        for (int j = 0; j < 4; ++j) {
            int er = mi * 16 + lg * 4 + j;
            int dst = ei_dst[e0 + er];
            float sc = invdeg[r * N_NODES + dst];
            float* op = out + (size_t)dst * D + colbase + lr;
#pragma unroll
            for (int ni = 0; ni < 4; ++ni)
                atomicAdd(op + ni * 16, acc[mi][ni][j] * sc);
        }
    }
}

// out = x @ w_self + b_self.  grid = ceil(N/64)
__global__ __launch_bounds__(256) void k_self(const float* __restrict__ x,
                                              const ushort* __restrict__ Wt,
                                              const float* __restrict__ bias,
                                              float* __restrict__ out) {
    __shared__ short8 xs[64 * 32];
    int t = threadIdx.x;
    int row0 = blockIdx.x * 64;
    {
        int c = t & 31, rbase = t >> 5;
        for (int i = 0; i < 8; ++i) {
            int rr = i * 8 + rbase;
            int src = min(row0 + rr, N_NODES - 1);
            stage_row(xs, x + (size_t)src * D, rr, c);
        }
    }
    __syncthreads();
    int l = t & 63, w = t >> 6;
    int colbase = w * 64;
    int lr = l & 15, lg = l >> 4;
    f32x4 acc[4][4] = {};
    for (int kk = 0; kk < 8; ++kk) {
        short8 a[4], b[4];
#pragma unroll
        for (int mi = 0; mi < 4; ++mi) {
            int row = mi * 16 + lr;
            int ch = kk * 4 + lg;
            a[mi] = xs[row * 32 + (ch ^ (row & 7))];
        }
#pragma unroll
        for (int ni = 0; ni < 4; ++ni) {
            int col = colbase + ni * 16 + lr;
            b[ni] = *reinterpret_cast<const short8*>(Wt + (size_t)col * D + kk * 32 + lg * 8);
        }
#pragma unroll
        for (int mi = 0; mi < 4; ++mi)
#pragma unroll
            for (int ni = 0; ni < 4; ++ni)
                acc[mi][ni] = __builtin_amdgcn_mfma_f32_16x16x32_bf16(
                    a[mi], b[ni], acc[mi][ni], 0, 0, 0);
    }
    float bv[4];
#pragma unroll
    for (int ni = 0; ni < 4; ++ni) bv[ni] = bias[colbase + ni * 16 + lr];
#pragma unroll
    for (int mi = 0; mi < 4; ++mi) {
#pragma unroll
        for (int j = 0; j < 4; ++j) {
            int row = row0 + mi * 16 + lg * 4 + j;
            if (row < N_NODES) {
                float* op = out + (size_t)row * D + colbase + lr;
#pragma unroll
                for (int ni = 0; ni < 4; ++ni) op[ni * 16] = acc[mi][ni][j] + bv[ni];
            }
        }
    }
}

// ---------------------------------------------------------------------------
// in-place SiLU + LayerNorm, one wave per row
__global__ __launch_bounds__(256) void k_ln(float* __restrict__ out,
                                            const float* __restrict__ gamma,
                                            const float* __restrict__ beta) {
    int t = threadIdx.x;
    int lane = t & 63, wv = t >> 6;
    int row = blockIdx.x * 4 + wv;
    size_t ro = (size_t)row * D + lane * 4;
    float4 h4 = *(const float4*)&out[ro];
    float a[4];
    a[0] = h4.x / (1.f + expf(-h4.x));
    a[1] = h4.y / (1.f + expf(-h4.y));
    a[2] = h4.z / (1.f + expf(-h4.z));
    a[3] = h4.w / (1.f + expf(-h4.w));
    float s = a[0] + a[1] + a[2] + a[3];
#pragma unroll
    for (int off = 32; off >= 1; off >>= 1) s += __shfl_xor(s, off, 64);
    float mean = s * (1.0f / 256.0f);
    float v = 0.f;
#pragma unroll
    for (int j = 0; j < 4; ++j) { float dd = a[j] - mean; v += dd * dd; }
#pragma unroll
    for (int off = 32; off >= 1; off >>= 1) v += __shfl_xor(v, off, 64);
    float rs = rsqrtf(v * (1.0f / 256.0f) + LN_EPS);
    float4 g4 = *(const float4*)&gamma[lane * 4];
    float4 b4 = *(const float4*)&beta[lane * 4];
    float4 o4;
    o4.x = (a[0] - mean) * rs * g4.x + b4.x;
    o4.y = (a[1] - mean) * rs * g4.y + b4.y;
    o4.z = (a[2] - mean) * rs * g4.z + b4.z;
    o4.w = (a[3] - mean) * rs * g4.w + b4.w;
    *(float4*)&out[ro] = o4;
}

// ---------------------------------------------------------------------------
extern "C" void kernel_launch(void* const* d_in, const int* in_sizes, int n_in,
                              void* d_out, int out_size, void* d_ws, size_t ws_size,
                              hipStream_t stream) {
    const float* x      = (const float*)d_in[0];
    const int*   ei     = (const int*)d_in[1];
    const float* bases  = (const float*)d_in[2];
    const float* coeff  = (const float*)d_in[3];
    const float* w_self = (const float*)d_in[4];
    const float* b_self = (const float*)d_in[5];
    const float* gamma  = (const float*)d_in[6];
    const float* beta   = (const float*)d_in[7];
    float* out = (float*)d_out;

    ushort* Wt  = (ushort*)d_ws;                         // R*D*D bf16 (1 MB)
    ushort* WtS = Wt + (size_t)R_REL * D * D;            // D*D bf16 (128 KB)
    float*  deg = (float*)(WtS + (size_t)D * D);         // R*N f32 (3.2 MB)

    hipMemsetAsync(deg, 0, (size_t)R_REL * N_NODES * sizeof(float), stream);

    k_prepW<<<R_REL * 16, 256, 0, stream>>>(bases, coeff, Wt);
    k_wselfT<<<16, 256, 0, stream>>>(w_self, WtS);
    k_count<<<(R_REL * E_EDGES + 255) / 256, 256, 0, stream>>>(ei, deg);
    k_invdeg<<<(R_REL * N_NODES + 255) / 256, 256, 0, stream>>>(deg);
    k_self<<<(N_NODES + 63) / 64, 256, 0, stream>>>(x, WtS, b_self, out);
    k_edge<<<R_REL * (E_EDGES / 64), 256, 0, stream>>>(x, ei, Wt, deg, out);
    k_ln<<<N_NODES / 4, 256, 0, stream>>>(out, gamma, beta);
}

// Round 3
// 357.871 us; speedup vs baseline: 2.5047x; 1.2499x over previous
//
#include <hip/hip_runtime.h>
#include <hip/hip_bf16.h>
#include <hip/hip_fp16.h>

#define N_NODES 100000
#define D 256
#define R_REL 8
#define E_EDGES 40000
#define B_BASES 4
#define LN_EPS 1e-5f

typedef __attribute__((ext_vector_type(8))) short short8;
typedef __attribute__((ext_vector_type(4))) float f32x4;

__device__ inline short bf16_of(float f) {
    __hip_bfloat16 h = __float2bfloat16(f);
    return *reinterpret_cast<short*>(&h);
}

// ---------------------------------------------------------------------------
// Wt[r][o][d] = sum_b coeff[r,b] * bases[b][d][o]   (bf16, transposed)
__global__ __launch_bounds__(256) void k_prepW(const float* __restrict__ bases,
                                               const float* __restrict__ coeff,
                                               ushort* __restrict__ Wt) {
    __shared__ float tile[64][65];
    int r  = blockIdx.x >> 4;
    int dt = (blockIdx.x >> 2) & 3, ot = blockIdx.x & 3;
    int t = threadIdx.x;
    float c0 = coeff[r * 4 + 0], c1 = coeff[r * 4 + 1];
    float c2 = coeff[r * 4 + 2], c3 = coeff[r * 4 + 3];
    int cl = t & 63, rw = t >> 6;
    for (int i = 0; i < 16; ++i) {
        int dl = i * 4 + rw;
        size_t gi = (size_t)(dt * 64 + dl) * D + ot * 64 + cl;
        tile[dl][cl] = c0 * bases[gi] + c1 * bases[65536 + gi]
                     + c2 * bases[2 * 65536 + gi] + c3 * bases[3 * 65536 + gi];
    }
    __syncthreads();
    for (int i = 0; i < 16; ++i) {
        int ol = i * 4 + rw;
        Wt[(size_t)r * 65536 + (size_t)(ot * 64 + ol) * D + dt * 64 + cl] =
            (ushort)bf16_of(tile[cl][ol]);
    }
}

// wt_self[o][d] = bf16(w_self[d][o])
__global__ __launch_bounds__(256) void k_wselfT(const float* __restrict__ w,
                                                ushort* __restrict__ Wt) {
    __shared__ float tile[64][65];
    int dt = blockIdx.x >> 2, ot = blockIdx.x & 3;
    int t = threadIdx.x;
    int cl = t & 63, rw = t >> 6;
    for (int i = 0; i < 16; ++i) {
        int dl = i * 4 + rw;
        tile[dl][cl] = w[(size_t)(dt * 64 + dl) * D + ot * 64 + cl];
    }
    __syncthreads();
    for (int i = 0; i < 16; ++i) {
        int ol = i * 4 + rw;
        Wt[(size_t)(ot * 64 + ol) * D + dt * 64 + cl] = (ushort)bf16_of(tile[cl][ol]);
    }
}

// ---------------------------------------------------------------------------
__global__ void k_count(const int* __restrict__ ei, float* __restrict__ deg) {
    int idx = blockIdx.x * blockDim.x + threadIdx.x;
    if (idx >= R_REL * E_EDGES) return;
    int r = idx / E_EDGES, e = idx % E_EDGES;
    int dst = ei[(r * 2 + 1) * E_EDGES + e];
    atomicAdd(&deg[r * N_NODES + dst], 1.0f);
}

__global__ void k_invdeg(float* __restrict__ deg) {
    int idx = blockIdx.x * blockDim.x + threadIdx.x;
    if (idx < R_REL * N_NODES) deg[idx] = 1.0f / fmaxf(deg[idx], 1.0f);
}

// ---------------------------------------------------------------------------
// LDS staging: xs[row][chunk] of short8, chunk XOR-swizzled by row.
__device__ inline void stage_row(short8* xs, const float* __restrict__ src_row,
                                 int rr, int c) {
    const float4* xp = (const float4*)(src_row + c * 8);
    float4 f0 = xp[0], f1 = xp[1];
    short8 v;
    v[0] = bf16_of(f0.x); v[1] = bf16_of(f0.y); v[2] = bf16_of(f0.z); v[3] = bf16_of(f0.w);
    v[4] = bf16_of(f1.x); v[5] = bf16_of(f1.y); v[6] = bf16_of(f1.z); v[7] = bf16_of(f1.w);
    xs[rr * 32 + (c ^ (rr & 7))] = v;
}

// msg = x[src] @ W_r; packed-f16 atomic scatter (*inv_deg) into acc.
// acc h2 layout per node: slot = dst*128 + w*32 + pair*16 + lr,
//   pair0 = cols (w*64+lr, w*64+16+lr), pair1 = (+32, +48).
__global__ __launch_bounds__(256) void k_edge(const float* __restrict__ x,
                                              const int* __restrict__ ei,
                                              const ushort* __restrict__ Wt,
                                              const float* __restrict__ invdeg,
                                              __half2* __restrict__ accb) {
    __shared__ short8 xs[64 * 32];               // 32 KB
    int t = threadIdx.x;
    const int CHUNKS = E_EDGES / 64;             // 625
    int r = blockIdx.x / CHUNKS;
    int e0 = (blockIdx.x % CHUNKS) * 64;
    const int* ei_src = ei + r * 2 * E_EDGES;
    const int* ei_dst = ei_src + E_EDGES;
    {
        int c = t & 31, rbase = t >> 5;
        for (int i = 0; i < 8; ++i) {
            int rr = i * 8 + rbase;
            int src = ei_src[e0 + rr];
            stage_row(xs, x + (size_t)src * D, rr, c);
        }
    }
    __syncthreads();
    int l = t & 63, w = t >> 6;
    int colbase = w * 64;
    int lr = l & 15, lg = l >> 4;
    const ushort* Wr = Wt + (size_t)r * D * D;
    f32x4 acc[4][4] = {};
    for (int kk = 0; kk < 8; ++kk) {
        short8 a[4], b[4];
#pragma unroll
        for (int mi = 0; mi < 4; ++mi) {
            int row = mi * 16 + lr;
            int ch = kk * 4 + lg;
            a[mi] = xs[row * 32 + (ch ^ (row & 7))];
        }
#pragma unroll
        for (int ni = 0; ni < 4; ++ni) {
            int col = colbase + ni * 16 + lr;
            b[ni] = *reinterpret_cast<const short8*>(Wr + (size_t)col * D + kk * 32 + lg * 8);
        }
#pragma unroll
        for (int mi = 0; mi < 4; ++mi)
#pragma unroll
            for (int ni = 0; ni < 4; ++ni)
                acc[mi][ni] = __builtin_amdgcn_mfma_f32_16x16x32_bf16(
                    a[mi], b[ni], acc[mi][ni], 0, 0, 0);
    }
#pragma unroll
    for (int mi = 0; mi < 4; ++mi) {
#pragma unroll
        for (int j = 0; j < 4; ++j) {
            int er = mi * 16 + lg * 4 + j;
            int dst = ei_dst[e0 + er];
            float sc = invdeg[r * N_NODES + dst];
            __half2* ap = accb + (size_t)dst * 128 + w * 32 + lr;
            unsafeAtomicAdd(ap,      __floats2half2_rn(acc[mi][0][j] * sc, acc[mi][1][j] * sc));
            unsafeAtomicAdd(ap + 16, __floats2half2_rn(acc[mi][2][j] * sc, acc[mi][3][j] * sc));
        }
    }
}

// ---------------------------------------------------------------------------
// out = LN(SiLU(x @ w_self + b_self + acc)) — fused, 64 rows per block.
__global__ __launch_bounds__(256) void k_fused(const float* __restrict__ x,
                                               const ushort* __restrict__ Wt,
                                               const float* __restrict__ bias,
                                               const __half2* __restrict__ accb,
                                               const float* __restrict__ gamma,
                                               const float* __restrict__ beta,
                                               float* __restrict__ out) {
    __shared__ short8 xs[64 * 32];
    __shared__ float red[2][64][4];
    int t = threadIdx.x;
    int row0 = blockIdx.x * 64;
    {
        int c = t & 31, rbase = t >> 5;
        for (int i = 0; i < 8; ++i) {
            int rr = i * 8 + rbase;
            int src = min(row0 + rr, N_NODES - 1);
            stage_row(xs, x + (size_t)src * D, rr, c);
        }
    }
    __syncthreads();
    int l = t & 63, w = t >> 6;
    int colbase = w * 64;
    int lr = l & 15, lg = l >> 4;
    f32x4 acc[4][4] = {};
    for (int kk = 0; kk < 8; ++kk) {
        short8 a[4], b[4];
#pragma unroll
        for (int mi = 0; mi < 4; ++mi) {
            int row = mi * 16 + lr;
            int ch = kk * 4 + lg;
            a[mi] = xs[row * 32 + (ch ^ (row & 7))];
        }
#pragma unroll
        for (int ni = 0; ni < 4; ++ni) {
            int col = colbase + ni * 16 + lr;
            b[ni] = *reinterpret_cast<const short8*>(Wt + (size_t)col * D + kk * 32 + lg * 8);
        }
#pragma unroll
        for (int mi = 0; mi < 4; ++mi)
#pragma unroll
            for (int ni = 0; ni < 4; ++ni)
                acc[mi][ni] = __builtin_amdgcn_mfma_f32_16x16x32_bf16(
                    a[mi], b[ni], acc[mi][ni], 0, 0, 0);
    }
    float bv[4];
#pragma unroll
    for (int ni = 0; ni < 4; ++ni) bv[ni] = bias[colbase + ni * 16 + lr];
    // + acc, SiLU in place; per-row partial sums
#pragma unroll
    for (int mi = 0; mi < 4; ++mi) {
#pragma unroll
        for (int j = 0; j < 4; ++j) {
            int rl = mi * 16 + lg * 4 + j;
            int rg = min(row0 + rl, N_NODES - 1);
            const __half2* ap = accb + (size_t)rg * 128 + w * 32 + lr;
            float2 p0 = __half22float2(ap[0]);
            float2 p1 = __half22float2(ap[16]);
            float va[4];
            va[0] = acc[mi][0][j] + bv[0] + p0.x;
            va[1] = acc[mi][1][j] + bv[1] + p0.y;
            va[2] = acc[mi][2][j] + bv[2] + p1.x;
            va[3] = acc[mi][3][j] + bv[3] + p1.y;
            float s = 0.f, q = 0.f;
#pragma unroll
            for (int ni = 0; ni < 4; ++ni) {
                float aa = va[ni] / (1.f + expf(-va[ni]));
                acc[mi][ni][j] = aa;          // keep SiLU'd value
                s += aa; q += aa * aa;
            }
#pragma unroll
            for (int off = 1; off < 16; off <<= 1) {
                s += __shfl_xor(s, off, 64);
                q += __shfl_xor(q, off, 64);
            }
            if (lr == 0) { red[0][rl][w] = s; red[1][rl][w] = q; }
        }
    }
    __syncthreads();
    float gv[4], bt[4];
#pragma unroll
    for (int ni = 0; ni < 4; ++ni) {
        gv[ni] = gamma[colbase + ni * 16 + lr];
        bt[ni] = beta[colbase + ni * 16 + lr];
    }
#pragma unroll
    for (int mi = 0; mi < 4; ++mi) {
#pragma unroll
        for (int j = 0; j < 4; ++j) {
            int rl = mi * 16 + lg * 4 + j;
            int rg = row0 + rl;
            if (rg >= N_NODES) continue;
            float s = red[0][rl][0] + red[0][rl][1] + red[0][rl][2] + red[0][rl][3];
            float q = red[1][rl][0] + red[1][rl][1] + red[1][rl][2] + red[1][rl][3];
            float mean = s * (1.0f / 256.0f);
            float var = q * (1.0f / 256.0f) - mean * mean;
            float rs = rsqrtf(var + LN_EPS);
            float* op = out + (size_t)rg * D + colbase + lr;
#pragma unroll
            for (int ni = 0; ni < 4; ++ni)
                op[ni * 16] = (acc[mi][ni][j] - mean) * rs * gv[ni] + bt[ni];
        }
    }
}

// ---------------------------------------------------------------------------
extern "C" void kernel_launch(void* const* d_in, const int* in_sizes, int n_in,
                              void* d_out, int out_size, void* d_ws, size_t ws_size,
                              hipStream_t stream) {
    const float* x      = (const float*)d_in[0];
    const int*   ei     = (const int*)d_in[1];
    const float* bases  = (const float*)d_in[2];
    const float* coeff  = (const float*)d_in[3];
    const float* w_self = (const float*)d_in[4];
    const float* b_self = (const float*)d_in[5];
    const float* gamma  = (const float*)d_in[6];
    const float* beta   = (const float*)d_in[7];
    float* out = (float*)d_out;

    ushort* Wt  = (ushort*)d_ws;                          // R*D*D bf16 (1 MB)
    ushort* WtS = Wt + (size_t)R_REL * D * D;             // D*D bf16 (128 KB)
    float*  deg = (float*)(WtS + (size_t)D * D);          // R*N f32 (3.2 MB)
    __half2* accb = (__half2*)(deg + (size_t)R_REL * N_NODES);  // N*128 h2 (51.2 MB)

    hipMemsetAsync(deg, 0, (size_t)R_REL * N_NODES * sizeof(float), stream);
    hipMemsetAsync(accb, 0, (size_t)N_NODES * 128 * sizeof(__half2), stream);

    k_prepW<<<R_REL * 16, 256, 0, stream>>>(bases, coeff, Wt);
    k_wselfT<<<16, 256, 0, stream>>>(w_self, WtS);
    k_count<<<(R_REL * E_EDGES + 255) / 256, 256, 0, stream>>>(ei, deg);
    k_invdeg<<<(R_REL * N_NODES + 255) / 256, 256, 0, stream>>>(deg);
    k_edge<<<R_REL * (E_EDGES / 64), 256, 0, stream>>>(x, ei, Wt, deg, accb);
    k_fused<<<(N_NODES + 63) / 64, 256, 0, stream>>>(x, WtS, b_self, accb, gamma, beta, out);
}